// Round 8
// baseline (1749.439 us; speedup 1.0000x reference)
//
#include <hip/hip_runtime.h>
#include <hip/hip_bf16.h>

typedef __attribute__((ext_vector_type(8))) short short8;
typedef __attribute__((ext_vector_type(4))) float f32x4;
typedef unsigned short u16;

#define BSZ 32
#define LSEQ 2048
#define BL (BSZ*LSEQ)
#define DMODEL 256
#define DINNER 512
#define DSTATE 64
#define NH 8
#define HD 64
#define NC 32
#define CONVD 640
#define NPROJ 1160
#define DFFN 1024

static __device__ __forceinline__ float b2f(u16 v) {
  union { unsigned int u; float f; } x; x.u = ((unsigned int)v) << 16; return x.f;
}
static __device__ __forceinline__ u16 f2b(float f) {
  union { float f; unsigned int u; } x; x.f = f;
  unsigned int u = x.u;
  u += 0x7fffu + ((u >> 16) & 1u);   // round-to-nearest-even
  return (u16)(u >> 16);
}
static __device__ __forceinline__ float siluf(float x) { return x / (1.f + expf(-x)); }

// ---------------------------------------------------------------- cast f32->bf16
__global__ __launch_bounds__(256) void k_cast(const float* __restrict__ in,
                                              u16* __restrict__ out, int n) {
  int i = blockIdx.x * 256 + threadIdx.x;
  int stride = gridDim.x * 256;
  for (; i < n; i += stride) out[i] = f2b(in[i]);
}

// ---------------------------------------------------------------- GEMM  C = A @ W^T (+bias)
// A: [M,K] bf16 row-major.  W: [N,K] bf16 row-major.
// MODE 0: in_proj epilogue (split z / xBC / softplus-dt); 1: f32 out; 2: hardswish bf16
template<int MODE>
__global__ __launch_bounds__(256) void k_gemm(
    const u16* __restrict__ Am, const u16* __restrict__ Wm,
    const float* __restrict__ bias, int M, int N, int K,
    float* __restrict__ outF, u16* __restrict__ outB,
    u16* __restrict__ zout, u16* __restrict__ xbcout, float* __restrict__ dtout,
    const float* __restrict__ dt_bias)
{
  __shared__ __align__(16) u16 As[128*40];
  __shared__ __align__(16) u16 Ws[128*40];
  const int tid = threadIdx.x;
  const int m0 = blockIdx.x * 128;
  const int n0 = blockIdx.y * 128;
  const int lane = tid & 63;
  const int lm = lane & 15;
  const int lq = lane >> 4;
  const int wm = (tid >> 7) & 1;
  const int wn = (tid >> 6) & 1;
  const int r1 = tid >> 2;
  const int seg = tid & 3;

  const f32x4 zero4 = {0.f, 0.f, 0.f, 0.f};
  f32x4 acc[4][4];
#pragma unroll
  for (int i = 0; i < 4; ++i)
#pragma unroll
    for (int j = 0; j < 4; ++j) acc[i][j] = zero4;
  const short8 z8 = {0,0,0,0,0,0,0,0};

  for (int k0 = 0; k0 < K; k0 += 32) {
    __syncthreads();
    *(short8*)&As[r1*40 + seg*8] =
        *(const short8*)&Am[(size_t)(m0 + r1)*K + k0 + seg*8];
    *(short8*)&As[(r1+64)*40 + seg*8] =
        *(const short8*)&Am[(size_t)(m0 + r1 + 64)*K + k0 + seg*8];
    int nr1 = n0 + r1, nr2 = n0 + r1 + 64;
    short8 wv1 = z8, wv2 = z8;
    if (nr1 < N) wv1 = *(const short8*)&Wm[(size_t)nr1*K + k0 + seg*8];
    if (nr2 < N) wv2 = *(const short8*)&Wm[(size_t)nr2*K + k0 + seg*8];
    *(short8*)&Ws[r1*40 + seg*8] = wv1;
    *(short8*)&Ws[(r1+64)*40 + seg*8] = wv2;
    __syncthreads();
    short8 af[4], bfr[4];
#pragma unroll
    for (int m = 0; m < 4; ++m)
      af[m] = *(const short8*)&As[(wm*64 + m*16 + lm)*40 + lq*8];
#pragma unroll
    for (int n = 0; n < 4; ++n)
      bfr[n] = *(const short8*)&Ws[(wn*64 + n*16 + lm)*40 + lq*8];
#pragma unroll
    for (int m = 0; m < 4; ++m)
#pragma unroll
      for (int n = 0; n < 4; ++n)
        acc[m][n] = __builtin_amdgcn_mfma_f32_16x16x32_bf16(af[m], bfr[n], acc[m][n], 0, 0, 0);
  }

#pragma unroll
  for (int n = 0; n < 4; ++n) {
    int gcol = n0 + wn*64 + n*16 + lm;
    if (gcol >= N) continue;
    float bcol = bias[gcol];
#pragma unroll
    for (int m = 0; m < 4; ++m) {
#pragma unroll
      for (int j = 0; j < 4; ++j) {
        int grow = m0 + wm*64 + m*16 + lq*4 + j;   // C/D: row=(lane>>4)*4+j, col=lane&15
        float v = acc[m][n][j] + bcol;
        if (MODE == 0) {
          size_t row = (size_t)grow;
          if (gcol < 512) {
            zout[row*512 + gcol] = f2b(v);
          } else if (gcol < 1152) {
            xbcout[row*640 + (gcol - 512)] = f2b(v);
          } else {
            float t = v + dt_bias[gcol - 1152];
            float sp = (t > 20.f) ? t : log1pf(expf(t));
            dtout[row*8 + (gcol - 1152)] = sp;
          }
        } else if (MODE == 1) {
          outF[(size_t)grow*N + gcol] = v;
        } else {
          float hs = v * fminf(fmaxf(v + 3.f, 0.f), 6.f) * (1.f/6.f);
          outB[(size_t)grow*N + gcol] = f2b(hs);
        }
      }
    }
  }
}

// ---------------------------------------------------------------- causal conv(K=4) + SiLU + split
__global__ __launch_bounds__(256) void k_conv(
    const u16* __restrict__ xbc, const float* __restrict__ cw, const float* __restrict__ cb,
    u16* __restrict__ xs, u16* __restrict__ Bm, u16* __restrict__ Cm)
{
  const int b = blockIdx.x >> 5;          // chunk-local batch
  const int l0 = (blockIdx.x & 31) * 64;
  for (int idx = threadIdx.x; idx < 64*640; idx += 256) {
    int l = idx / 640;
    int cc = idx - l*640;
    int gl = l0 + l;
    float acc = cb[cc];
#pragma unroll
    for (int k = 0; k < 4; ++k) {
      int ll = gl - 3 + k;
      if (ll >= 0)
        acc += b2f(xbc[((size_t)b*LSEQ + ll)*640 + cc]) * cw[cc*4 + k];
    }
    u16 o = f2b(siluf(acc));
    size_t row = (size_t)b*LSEQ + gl;
    if (cc < 512)      xs[row*512 + cc] = o;
    else if (cc < 576) Bm[row*64 + (cc - 512)] = o;
    else               Cm[row*64 + (cc - 576)] = o;
  }
}

// ---------------------------------------------------------------- per-chunk cumsum of dA; chunk decay
__global__ __launch_bounds__(512) void k_acs(
    const float* __restrict__ dts, const float* __restrict__ A_log,
    float* __restrict__ A_cs, float* __restrict__ dec)
{
  const int b = blockIdx.x >> 5, c = blockIdx.x & 31;
  const int h = threadIdx.x >> 6, l = threadIdx.x & 63;
  float Ah = -expf(A_log[h]);
  float v = dts[((size_t)b*LSEQ + c*64 + l)*NH + h] * Ah;
#pragma unroll
  for (int off = 1; off < 64; off <<= 1) {
    float u = __shfl_up(v, off, 64);
    if (l >= off) v += u;
  }
  A_cs[(((size_t)b*NC + c)*NH + h)*64 + l] = v;
  if (l == 63) dec[((size_t)b*NH + h)*NC + c] = expf(v);
}

// ---------------------------------------------------------------- per-chunk states[p][n] (MFMA)
__global__ __launch_bounds__(256) void k_states(
    const u16* __restrict__ xs, const u16* __restrict__ Bm,
    const float* __restrict__ dts, const float* __restrict__ A_cs,
    u16* __restrict__ states)
{
  __shared__ __align__(16) u16 At[64*72];
  __shared__ __align__(16) u16 Bt[64*72];
  __shared__ float sc[64];
  const int bid = blockIdx.x;
  const int h = bid & 7, c = (bid >> 3) & 31, b = bid >> 8;
  const int tid = threadIdx.x;
  const float* acs = &A_cs[(((size_t)b*NC + c)*NH + h)*64];
  if (tid < 64) {
    float last = acs[63];
    sc[tid] = dts[((size_t)b*LSEQ + c*64 + tid)*NH + h] * expf(last - acs[tid]);
  }
  __syncthreads();
#pragma unroll
  for (int it = 0; it < 16; ++it) {
    int idx = it*256 + tid;
    int l = idx >> 6, p = idx & 63;
    size_t row = (size_t)b*LSEQ + c*64 + l;
    At[p*72 + l] = f2b(b2f(xs[row*512 + h*64 + p]) * sc[l]);
    Bt[p*72 + l] = Bm[row*64 + p];
  }
  __syncthreads();
  const int lm = tid & 15, lq = (tid >> 4) & 3;
  const int p0 = (tid >> 6) * 16;
  const f32x4 zero4 = {0.f,0.f,0.f,0.f};
  f32x4 acc[4] = {zero4, zero4, zero4, zero4};
#pragma unroll
  for (int k0 = 0; k0 < 64; k0 += 32) {
    short8 a = *(const short8*)&At[(p0 + lm)*72 + k0 + lq*8];
#pragma unroll
    for (int n = 0; n < 4; ++n) {
      short8 bb = *(const short8*)&Bt[(n*16 + lm)*72 + k0 + lq*8];
      acc[n] = __builtin_amdgcn_mfma_f32_16x16x32_bf16(a, bb, acc[n], 0, 0, 0);
    }
  }
  u16* so = &states[(((size_t)b*NC + c)*NH + h)*4096];
#pragma unroll
  for (int n = 0; n < 4; ++n)
#pragma unroll
    for (int j = 0; j < 4; ++j) {
      int p = p0 + lq*4 + j;
      so[p*64 + n*16 + lm] = f2b(acc[n][j]);
    }
}

// ---------------------------------------------------------------- inter-chunk scan IN-PLACE (st -> prev)
__global__ __launch_bounds__(256) void k_scan(
    u16* st, const float* __restrict__ dec)
{
  const int b = blockIdx.x >> 3, h = blockIdx.x & 7;
  const int tid = threadIdx.x;
  float carry[16];
#pragma unroll
  for (int i = 0; i < 16; ++i) carry[i] = 0.f;
  for (int c = 0; c < NC; ++c) {
    size_t base = (((size_t)b*NC + c)*NH + h)*4096;
    float dc = dec[((size_t)b*NH + h)*NC + c];
#pragma unroll
    for (int i = 0; i < 16; ++i) {
      size_t e = base + tid + i*256;
      float s = b2f(st[e]);          // read before overwrite (same thread)
      st[e] = f2b(carry[i]);
      carry[i] = carry[i]*dc + s;
    }
  }
}

// ---------------------------------------------------------------- Y = (L ⊙ CB^T) Xd + exp(Acs)·C·prev^T + Dp·X
__global__ __launch_bounds__(256) void k_ydiag(
    const u16* __restrict__ xs, const u16* __restrict__ Bm, const u16* __restrict__ Cm,
    const float* __restrict__ dts, const float* __restrict__ A_cs,
    const u16* __restrict__ prev, const float* __restrict__ Dp,
    u16* __restrict__ Ybuf)
{
  __shared__ __align__(16) u16 Cc[64*72], CcE[64*72], Bc[64*72], Mm[64*72], XdT[64*72];
  __shared__ float acs[64], eA[64];
  const int bid = blockIdx.x;
  const int h = bid & 7, c = (bid >> 3) & 31, b = bid >> 8;
  const int tid = threadIdx.x;
  const float* acsg = &A_cs[(((size_t)b*NC + c)*NH + h)*64];
  if (tid < 64) { float a = acsg[tid]; acs[tid] = a; eA[tid] = expf(a); }
  __syncthreads();
#pragma unroll
  for (int it = 0; it < 16; ++it) {
    int idx = it*256 + tid;
    int l = idx >> 6, n = idx & 63;
    size_t row = (size_t)b*LSEQ + c*64 + l;
    u16 cv = Cm[row*64 + n];
    Cc[l*72 + n]  = cv;
    CcE[l*72 + n] = f2b(b2f(cv) * eA[l]);
    Bc[l*72 + n]  = Bm[row*64 + n];
    XdT[n*72 + l] = f2b(b2f(xs[row*512 + h*64 + n]) * dts[row*NH + h]);
  }
  __syncthreads();
  const int lm = tid & 15, lq = (tid >> 4) & 3;
  const int l0 = (tid >> 6) * 16;
  const f32x4 zero4 = {0.f,0.f,0.f,0.f};
  f32x4 g[4] = {zero4, zero4, zero4, zero4};
#pragma unroll
  for (int k0 = 0; k0 < 64; k0 += 32) {
    short8 a = *(const short8*)&Cc[(l0 + lm)*72 + k0 + lq*8];
#pragma unroll
    for (int s = 0; s < 4; ++s) {
      short8 bb = *(const short8*)&Bc[(s*16 + lm)*72 + k0 + lq*8];
      g[s] = __builtin_amdgcn_mfma_f32_16x16x32_bf16(a, bb, g[s], 0, 0, 0);
    }
  }
#pragma unroll
  for (int s4 = 0; s4 < 4; ++s4)
#pragma unroll
    for (int j = 0; j < 4; ++j) {
      int l = l0 + lq*4 + j;
      int s = s4*16 + lm;
      float v = (s <= l) ? g[s4][j] * expf(acs[l] - acs[s]) : 0.f;
      Mm[l*72 + s] = f2b(v);
    }
  __syncthreads();
  f32x4 y[4] = {zero4, zero4, zero4, zero4};
#pragma unroll
  for (int k0 = 0; k0 < 64; k0 += 32) {
    short8 a = *(const short8*)&Mm[(l0 + lm)*72 + k0 + lq*8];
#pragma unroll
    for (int p4 = 0; p4 < 4; ++p4) {
      short8 bb = *(const short8*)&XdT[(p4*16 + lm)*72 + k0 + lq*8];
      y[p4] = __builtin_amdgcn_mfma_f32_16x16x32_bf16(a, bb, y[p4], 0, 0, 0);
    }
  }
  const u16* pv = &prev[(((size_t)b*NC + c)*NH + h)*4096];
#pragma unroll
  for (int k0 = 0; k0 < 64; k0 += 32) {
    short8 a = *(const short8*)&CcE[(l0 + lm)*72 + k0 + lq*8];
#pragma unroll
    for (int p4 = 0; p4 < 4; ++p4) {
      short8 bb = *(const short8*)&pv[(p4*16 + lm)*64 + k0 + lq*8];
      y[p4] = __builtin_amdgcn_mfma_f32_16x16x32_bf16(a, bb, y[p4], 0, 0, 0);
    }
  }
  float dph = Dp[h];
#pragma unroll
  for (int p4 = 0; p4 < 4; ++p4)
#pragma unroll
    for (int j = 0; j < 4; ++j) {
      int l = l0 + lq*4 + j;
      int p = p4*16 + lm;
      size_t row = (size_t)b*LSEQ + c*64 + l;
      float v = y[p4][j] + dph * b2f(xs[row*512 + h*64 + p]);
      Ybuf[row*512 + h*64 + p] = f2b(v);
    }
}

// ---------------------------------------------------------------- gated RMSNorm -> bf16
__global__ __launch_bounds__(256) void k_rms(
    const u16* __restrict__ Ybuf, const u16* __restrict__ zbf,
    const float* __restrict__ nw, u16* __restrict__ yb)
{
  __shared__ float red[4];
  const size_t r = blockIdx.x;
  const int tid = threadIdx.x;
  float zv0 = b2f(zbf[r*512 + tid]);
  float zv1 = b2f(zbf[r*512 + tid + 256]);
  float u0 = b2f(Ybuf[r*512 + tid]) * siluf(zv0);
  float u1 = b2f(Ybuf[r*512 + tid + 256]) * siluf(zv1);
  float ss = u0*u0 + u1*u1;
#pragma unroll
  for (int off = 32; off; off >>= 1) ss += __shfl_down(ss, off, 64);
  if ((tid & 63) == 0) red[tid >> 6] = ss;
  __syncthreads();
  float sc = rsqrtf((red[0] + red[1] + red[2] + red[3]) * (1.f/512.f) + 1e-12f);
  yb[r*512 + tid]       = f2b(u0 * sc * nw[tid]);
  yb[r*512 + tid + 256] = f2b(u1 * sc * nw[tid + 256]);
}

// ---------------------------------------------------------------- LayerNorm(a + res) (256 cols)
template<int WRITE_BF>
__global__ __launch_bounds__(256) void k_ln(
    const float* __restrict__ a, const float* __restrict__ res,
    const float* __restrict__ g, const float* __restrict__ bb,
    float* __restrict__ outF, u16* __restrict__ outB)
{
  __shared__ float redS[4], redQ[4];
  const size_t r = blockIdx.x;
  const int tid = threadIdx.x;
  float v = a[r*256 + tid] + res[r*256 + tid];
  float s = v, q = v*v;
#pragma unroll
  for (int off = 32; off; off >>= 1) {
    s += __shfl_down(s, off, 64);
    q += __shfl_down(q, off, 64);
  }
  if ((tid & 63) == 0) { redS[tid >> 6] = s; redQ[tid >> 6] = q; }
  __syncthreads();
  float S = redS[0] + redS[1] + redS[2] + redS[3];
  float Q = redQ[0] + redQ[1] + redQ[2] + redQ[3];
  float mean = S * (1.f/256.f);
  float var = fmaxf(Q * (1.f/256.f) - mean*mean, 0.f);
  float inv = rsqrtf(var + 1e-12f);
  float o = (v - mean) * inv * g[tid] + bb[tid];
  outF[r*256 + tid] = o;
  if (WRITE_BF) outB[r*256 + tid] = f2b(o);
}

// ================================================================ host
// ADAPTIVE workspace: footprint computed from ws_size; pipeline runs in
// batch-chunks of G in {32,16,8,4,2,1}. G=1 needs ~28 MB. No aliasing.
extern "C" void kernel_launch(void* const* d_in, const int* in_sizes, int n_in,
                              void* d_out, int out_size, void* d_ws, size_t ws_size,
                              hipStream_t stream)
{
  const float* x    = (const float*)d_in[0];
  const float* Wip  = (const float*)d_in[1];
  const float* bip  = (const float*)d_in[2];
  const float* cw   = (const float*)d_in[3];
  const float* cb   = (const float*)d_in[4];
  const float* dtb  = (const float*)d_in[5];
  const float* Alog = (const float*)d_in[6];
  const float* Dp   = (const float*)d_in[7];
  const float* nw   = (const float*)d_in[8];
  const float* Wop  = (const float*)d_in[9];
  const float* bop  = (const float*)d_in[10];
  const float* lng  = (const float*)d_in[11];
  const float* lnb  = (const float*)d_in[12];
  const float* W1   = (const float*)d_in[13];
  const float* b1   = (const float*)d_in[14];
  const float* W2   = (const float*)d_in[15];
  const float* b2   = (const float*)d_in[16];
  const float* flg  = (const float*)d_in[17];
  const float* flb  = (const float*)d_in[18];

  // ---- layout calculator for a chunk of G batches ----
  struct Off {
    size_t wip, wop, w1, w2;
    size_t xbf, zbf, xbc, dt, xs, bm, cm, acs, dec, st, y, yb, proj, hid, hidb, h1, h2;
    size_t total;
  };
  auto layout = [&](int G) -> Off {
    Off f; size_t o = 0;
    auto AL = [&](size_t n) { size_t r = o; o += (n + 255) & ~(size_t)255; return r; };
    const size_t M = (size_t)G * LSEQ;
    f.wip = AL((size_t)NPROJ*DMODEL*2);
    f.wop = AL((size_t)DMODEL*DINNER*2);
    f.w1  = AL((size_t)DFFN*DMODEL*2);
    f.w2  = AL((size_t)DMODEL*DFFN*2);
    f.xbf = AL(M*DMODEL*2);
    f.zbf = AL(M*DINNER*2);
    f.xbc = AL(M*CONVD*2);
    f.dt  = AL(M*NH*4);
    f.xs  = AL(M*DINNER*2);
    f.bm  = AL(M*DSTATE*2);
    f.cm  = AL(M*DSTATE*2);
    f.acs = AL((size_t)G*NC*NH*64*4);
    f.dec = AL((size_t)G*NH*NC*4);
    f.st  = AL((size_t)G*NC*NH*64*64*2);
    f.y   = AL(M*DINNER*2);
    f.yb  = AL(M*DINNER*2);
    f.proj= AL(M*DMODEL*4);
    f.hid = AL(M*DMODEL*4);
    f.hidb= AL(M*DMODEL*2);
    f.h1  = AL(M*DFFN*2);
    f.h2  = AL(M*DMODEL*4);
    f.total = o;
    return f;
  };

  int G = 1;
  {
    const int cand[5] = {32, 16, 8, 4, 2};
    for (int i = 0; i < 5; ++i) {
      if (layout(cand[i]).total <= ws_size) { G = cand[i]; break; }
    }
  }
  const Off f = layout(G);
  char* ws = (char*)d_ws;

  u16*   wipb = (u16*)(ws + f.wip);
  u16*   wopb = (u16*)(ws + f.wop);
  u16*   w1b  = (u16*)(ws + f.w1);
  u16*   w2b  = (u16*)(ws + f.w2);
  u16*   xbf  = (u16*)(ws + f.xbf);
  u16*   zbf  = (u16*)(ws + f.zbf);
  u16*   xbcb = (u16*)(ws + f.xbc);
  float* dts  = (float*)(ws + f.dt);
  u16*   xsb  = (u16*)(ws + f.xs);
  u16*   bmb  = (u16*)(ws + f.bm);
  u16*   cmb  = (u16*)(ws + f.cm);
  float* acsb = (float*)(ws + f.acs);
  float* decb = (float*)(ws + f.dec);
  u16*   stb  = (u16*)(ws + f.st);
  u16*   ybuf = (u16*)(ws + f.y);
  u16*   yb   = (u16*)(ws + f.yb);
  float* proj = (float*)(ws + f.proj);
  float* hid  = (float*)(ws + f.hid);
  u16*   hidb = (u16*)(ws + f.hidb);
  u16*   h1b  = (u16*)(ws + f.h1);
  float* h2   = (float*)(ws + f.h2);

  // weights cast once
  k_cast<<<512, 256, 0, stream>>>(Wip, wipb, NPROJ*DMODEL);
  k_cast<<<512, 256, 0, stream>>>(Wop, wopb, DMODEL*DINNER);
  k_cast<<<512, 256, 0, stream>>>(W1, w1b, DFFN*DMODEL);
  k_cast<<<512, 256, 0, stream>>>(W2, w2b, DMODEL*DFFN);

  const int M = G * LSEQ;
  for (int b0 = 0; b0 < BSZ; b0 += G) {
    const size_t rowOff = (size_t)b0 * LSEQ;           // row offset into full tensors
    const float* xg = x + rowOff * DMODEL;

    // cast x slice
    k_cast<<<1024, 256, 0, stream>>>(xg, xbf, M*DMODEL);

    // in_proj (split epilogue)
    dim3 gip(M/128, (NPROJ + 127)/128);
    k_gemm<0><<<gip, 256, 0, stream>>>(xbf, wipb, bip, M, NPROJ, DMODEL,
                                       nullptr, nullptr, zbf, xbcb, dts, dtb);
    // conv + SiLU + split
    k_conv<<<G*NC, 256, 0, stream>>>(xbcb, cw, cb, xsb, bmb, cmb);
    // cumsum dA, chunk decay
    k_acs<<<G*NC, 512, 0, stream>>>(dts, Alog, acsb, decb);
    // chunk states
    k_states<<<G*NC*NH, 256, 0, stream>>>(xsb, bmb, dts, acsb, stb);
    // inter-chunk scan in-place
    k_scan<<<G*NH, 256, 0, stream>>>(stb, decb);
    // Y
    k_ydiag<<<G*NC*NH, 256, 0, stream>>>(xsb, bmb, cmb, dts, acsb, stb, Dp, ybuf);
    // gated RMSNorm
    k_rms<<<M, 256, 0, stream>>>(ybuf, zbf, nw, yb);
    // out_proj
    dim3 gop(M/128, DMODEL/128);
    k_gemm<1><<<gop, 256, 0, stream>>>(yb, wopb, bop, M, DMODEL, DINNER,
                                       proj, nullptr, nullptr, nullptr, nullptr, nullptr);
    // LN1 (residual x slice)
    k_ln<1><<<M, 256, 0, stream>>>(proj, xg, lng, lnb, hid, hidb);
    // fc1 + hardswish
    dim3 g1(M/128, DFFN/128);
    k_gemm<2><<<g1, 256, 0, stream>>>(hidb, w1b, b1, M, DFFN, DMODEL,
                                      nullptr, h1b, nullptr, nullptr, nullptr, nullptr);
    // fc2
    dim3 g2(M/128, DMODEL/128);
    k_gemm<1><<<g2, 256, 0, stream>>>(h1b, w2b, b2, M, DMODEL, DFFN,
                                      h2, nullptr, nullptr, nullptr, nullptr, nullptr);
    // LN2 -> out slice
    k_ln<0><<<M, 256, 0, stream>>>(h2, hid, flg, flb,
                                   (float*)d_out + rowOff * DMODEL, nullptr);
  }
}